// Round 10
// baseline (181.734 us; speedup 1.0000x reference)
//
#include <hip/hip_runtime.h>
#include <hip/hip_bf16.h>
#include <math.h>

#define B_     16
#define C_     256
#define N_     1024
#define HEADS_ 4
#define DH_    32
#define INNER_ 128
#define EPS_   1e-5f

typedef __attribute__((ext_vector_type(8))) short bf16x8;
typedef __attribute__((ext_vector_type(4))) float f32x4;

__device__ __forceinline__ ushort f2bf(float f) {
  union { float f; unsigned u; } v; v.f = f;
  unsigned u = v.u;
  return (ushort)((u + 0x7fffu + ((u >> 16) & 1u)) >> 16);
}
__device__ __forceinline__ float bf2f(ushort u) {
  union { unsigned u; float f; } v; v.u = ((unsigned)u) << 16;
  return v.f;
}
__device__ __forceinline__ unsigned cvt_pk_bf16(float lo, float hi) {
  unsigned r;
  asm("v_cvt_pk_bf16_f32 %0, %1, %2" : "=v"(r) : "v"(lo), "v"(hi));
  return r;
}

// scale(1/sqrt(32)) * log2(e) folded into Q at QKV time.
// Fixed-base softmax: p = exp2(s) directly (scores bounded ~ +-9).
#define QSCALE_ 0.2550348652979437f

// ---------------- K0: weight convert + transpose to bf16 ----------------
__global__ __launch_bounds__(256) void k_wconv(
    const float* __restrict__ wqkv, const float* __restrict__ wout,
    const float* __restrict__ wff1, const float* __restrict__ wff2,
    ushort* __restrict__ wqkvT, ushort* __restrict__ woutT,
    ushort* __restrict__ wff1T, ushort* __restrict__ wff2T) {
  int i = blockIdx.x * 256 + threadIdx.x;
  if (i < 98304) {                       // w_qkv [256][384] -> [384][256]
    int k = i / 384, n = i % 384;
    wqkvT[n * 256 + k] = f2bf(wqkv[i]);
    return;
  }
  i -= 98304;
  if (i < 32768) {                       // w_out [128][256] -> [256][128]
    int k = i / 256, n = i % 256;
    woutT[n * 128 + k] = f2bf(wout[i]);
    return;
  }
  i -= 32768;
  if (i < 32768) {                       // w_ff1 [256][128] -> [128][256]
    int k = i / 128, n = i % 128;
    wff1T[n * 256 + k] = f2bf(wff1[i]);
    return;
  }
  i -= 32768;
  {                                      // w_ff2 [128][256] -> [256][128]
    int k = i / 256, n = i % 256;
    wff2T[n * 128 + k] = f2bf(wff2[i]);
  }
}

// ---------------- K1: fused pos+LN1+QKV (512 threads) ----------------
union KFusedSmem {
  float  xs[C_][68];      // 69,632 B  (stage A/B)
  ushort xnl[64][264];    // 33,792 B  (stage C)  -- aliased
};

__global__ __launch_bounds__(512) void k_fused(
    const float* __restrict__ x, const float* __restrict__ pos,
    const float* __restrict__ g1, const float* __restrict__ beta1,
    const ushort* __restrict__ wqkvT, ushort* __restrict__ tokb,
    ushort* __restrict__ qb, ushort* __restrict__ kb, ushort* __restrict__ vtb) {
  const int b  = blockIdx.x >> 4;
  const int n0 = (blockIdx.x & 15) << 6;
  const int t  = threadIdx.x;
  __shared__ KFusedSmem u;

  // ---- Stage A: load x tile 256c x 64n (coalesced, 8 float4/thread) ----
  {
    const int nq = t & 15, cq = t >> 4;          // cq 0..31
#pragma unroll
    for (int i = 0; i < 8; ++i) {
      const int c = i * 32 + cq;
      const float4 v = *reinterpret_cast<const float4*>(
          &x[((size_t)b * C_ + c) * N_ + n0 + 4 * nq]);
      *reinterpret_cast<float4*>(&u.xs[c][4 * nq]) = v;
    }
  }
  __syncthreads();

  // ---- Stage B: pos add + LN (8 threads per token, 32 ch each) ----
  {
    const int tl = t >> 3, sub = t & 7, c0 = sub * 32;
    const int n = n0 + tl;
    float v[32];
#pragma unroll
    for (int i = 0; i < 32; ++i) v[i] = u.xs[c0 + i][tl];
#pragma unroll
    for (int j = 0; j < 8; ++j) {
      const float4 p = *reinterpret_cast<const float4*>(&pos[(size_t)n * C_ + c0 + 4 * j]);
      v[4*j] += p.x; v[4*j+1] += p.y; v[4*j+2] += p.z; v[4*j+3] += p.w;
    }
    float s = 0.f;
#pragma unroll
    for (int i = 0; i < 32; ++i) s += v[i];
    s += __shfl_xor(s, 1); s += __shfl_xor(s, 2); s += __shfl_xor(s, 4);
    const float mu = s * (1.f / C_);
    float sq = 0.f;
#pragma unroll
    for (int i = 0; i < 32; ++i) { const float d = v[i] - mu; sq += d * d; }
    sq += __shfl_xor(sq, 1); sq += __shfl_xor(sq, 2); sq += __shfl_xor(sq, 4);
    const float rs = rsqrtf(sq * (1.f / C_) + EPS_);

    ushort* tokrow = &tokb[((size_t)b * N_ + n) * C_ + c0];
    ushort xn_local[32];
#pragma unroll
    for (int j = 0; j < 8; ++j) {
      ushort4 tu;
      tu.x = f2bf(v[4*j]);   tu.y = f2bf(v[4*j+1]);
      tu.z = f2bf(v[4*j+2]); tu.w = f2bf(v[4*j+3]);
      *reinterpret_cast<ushort4*>(&tokrow[4 * j]) = tu;
      const float4 g  = *reinterpret_cast<const float4*>(&g1[c0 + 4 * j]);
      const float4 be = *reinterpret_cast<const float4*>(&beta1[c0 + 4 * j]);
      xn_local[4*j]   = f2bf((v[4*j]   - mu) * rs * g.x + be.x);
      xn_local[4*j+1] = f2bf((v[4*j+1] - mu) * rs * g.y + be.y);
      xn_local[4*j+2] = f2bf((v[4*j+2] - mu) * rs * g.z + be.z);
      xn_local[4*j+3] = f2bf((v[4*j+3] - mu) * rs * g.w + be.w);
    }
    __syncthreads();   // all xs reads complete before aliased writes
#pragma unroll
    for (int j = 0; j < 8; ++j)
      *reinterpret_cast<ushort4*>(&u.xnl[tl][c0 + 4 * j]) =
          *reinterpret_cast<ushort4*>(&xn_local[4 * j]);
  }
  __syncthreads();

  // ---- Stage C: QKV GEMM (M=384 ch, N=64 tok, K=256); wave w -> 48 ch ----
  {
    const int w = t >> 6, lane = t & 63;
    const int li = lane & 15, g = lane >> 4;
#pragma unroll
    for (int mf = 0; mf < 3; ++mf) {
      const int chb = w * 48 + mf * 16;
      bf16x8 Af[8];
#pragma unroll
      for (int ks = 0; ks < 8; ++ks)
        Af[ks] = *reinterpret_cast<const bf16x8*>(
            &wqkvT[(size_t)(chb + li) * C_ + ks * 32 + 8 * g]);
#pragma unroll
      for (int nf = 0; nf < 4; ++nf) {
        bf16x8 Bf[8];
#pragma unroll
        for (int ks = 0; ks < 8; ++ks)
          Bf[ks] = *reinterpret_cast<const bf16x8*>(&u.xnl[nf * 16 + li][ks * 32 + 8 * g]);
        f32x4 acc = {0.f, 0.f, 0.f, 0.f};
#pragma unroll
        for (int ks = 0; ks < 8; ++ks)
          acc = __builtin_amdgcn_mfma_f32_16x16x32_bf16(Af[ks], Bf[ks], acc, 0, 0, 0);
        const int nn = n0 + nf * 16 + li;
        const int ch0 = chb + 4 * g;
        if (ch0 < 128) {                        // q, prescaled
          const int h = ch0 >> 5, dh = ch0 & 31;
          ushort4 uq;
          uq.x = f2bf(acc[0] * QSCALE_); uq.y = f2bf(acc[1] * QSCALE_);
          uq.z = f2bf(acc[2] * QSCALE_); uq.w = f2bf(acc[3] * QSCALE_);
          *reinterpret_cast<ushort4*>(&qb[(((size_t)(b * HEADS_ + h)) * N_ + nn) * DH_ + dh]) = uq;
        } else if (ch0 < 256) {
          const int c2 = ch0 - 128, h = c2 >> 5, dh = c2 & 31;
          ushort4 uk;
          uk.x = f2bf(acc[0]); uk.y = f2bf(acc[1]); uk.z = f2bf(acc[2]); uk.w = f2bf(acc[3]);
          *reinterpret_cast<ushort4*>(&kb[(((size_t)(b * HEADS_ + h)) * N_ + nn) * DH_ + dh]) = uk;
        } else {
          const int c2 = ch0 - 256, h = c2 >> 5, dh = c2 & 31;
          ushort* base = &vtb[(((size_t)(b * HEADS_ + h)) * DH_ + dh) * N_ + nn];
          base[0] = f2bf(acc[0]); base[N_] = f2bf(acc[1]);
          base[2 * N_] = f2bf(acc[2]); base[3 * N_] = f2bf(acc[3]);
        }
      }
    }
  }
}

// ---------------- K2: merged attention + MLP, 16-token tiles ----------------
// grid 1024 = (b, 16-token tile) -> 4 blocks/CU co-resident (LDS 29.4 KB).
// block 256 = 4 waves; wave w = head w, 16 queries each. No reg prefetch:
// 4 waves/SIMD provide the latency hiding (R6 prefetch was ~0 gain at 2/SIMD).
__global__ __launch_bounds__(256) void k_attn_mlp(
    const ushort* __restrict__ qb, const ushort* __restrict__ kb,
    const ushort* __restrict__ vtb, const ushort* __restrict__ tokb,
    const ushort* __restrict__ woutT, const float* __restrict__ b_out,
    const ushort* __restrict__ wff1T, const float* __restrict__ b_ff1,
    const ushort* __restrict__ wff2T, const float* __restrict__ b_ff2,
    const float* __restrict__ g2, const float* __restrict__ beta2,
    float* __restrict__ out) {
  const int b   = blockIdx.x >> 6;
  const int tt  = blockIdx.x & 63;
  const int nq0 = tt * 16;
  const int tid = threadIdx.x;
  const int w = tid >> 6, lane = tid & 63;
  const int qi = lane & 15, g = lane >> 4;

  __shared__ __align__(16) union {
    ushort P[4][16][72];      // attn P round-trip       (9,216 B)
    float  t2s[16][260];      // MLP fp32 residual      (16,640 B)
  } u1;
  __shared__ __align__(16) ushort xn2[16][264];   // LN2 out (8,448 B)
  __shared__ __align__(16) union {
    ushort aos[16][136];      // attn output tile        (4,352 B)
    ushort hsb[16][136];      // gelu output (aliased)
  } u2;

  // ================= attention (wave w = head w, 16 queries) =================
  {
    const int bh = b * HEADS_ + w;
    const ushort* Kb = kb  + (size_t)bh * N_ * DH_;
    const ushort* Vt = vtb + (size_t)bh * DH_ * N_;

    const bf16x8 qf = *reinterpret_cast<const bf16x8*>(
        qb + ((size_t)bh * N_ + nq0 + qi) * DH_ + 8 * g);

    f32x4 acc[2];
#pragma unroll
    for (int d = 0; d < 2; ++d)
#pragma unroll
      for (int r = 0; r < 4; ++r) acc[d][r] = 0.f;
    float l = 0.f;

    for (int jt = 0; jt < 16; ++jt) {
      const int k0 = jt * 64;

      // ---- S^T = K.Q^T (4 MFMAs over 64 keys) ----
      f32x4 s[4];
#pragma unroll
      for (int kt = 0; kt < 4; ++kt) {
        const bf16x8 kf = *reinterpret_cast<const bf16x8*>(
            Kb + (size_t)(k0 + kt * 16 + qi) * DH_ + 8 * g);
        f32x4 z = {0.f, 0.f, 0.f, 0.f};
        s[kt] = __builtin_amdgcn_mfma_f32_16x16x32_bf16(kf, qf, z, 0, 0, 0);
      }

      // ---- fixed-base softmax: p = exp2(s), all independent ----
      float psum = 0.f;
#pragma unroll
      for (int kt = 0; kt < 4; ++kt) {
        const float p0 = exp2f(s[kt][0]);
        const float p1 = exp2f(s[kt][1]);
        const float p2 = exp2f(s[kt][2]);
        const float p3 = exp2f(s[kt][3]);
        psum += (p0 + p1) + (p2 + p3);
        uint2 dw;
        dw.x = cvt_pk_bf16(p0, p1);
        dw.y = cvt_pk_bf16(p2, p3);
        *reinterpret_cast<uint2*>(&u1.P[w][qi][kt * 16 + 4 * g]) = dw;
      }
      l += psum;

      // ---- O^T += Vt . P^T (4 loads + 4 MFMAs) ----
#pragma unroll
      for (int c = 0; c < 2; ++c) {
        const bf16x8 pf = *reinterpret_cast<const bf16x8*>(&u1.P[w][qi][c * 32 + 8 * g]);
#pragma unroll
        for (int d = 0; d < 2; ++d) {
          const bf16x8 vf = *reinterpret_cast<const bf16x8*>(
              Vt + (size_t)(d * 16 + qi) * N_ + k0 + c * 32 + 8 * g);
          acc[d] = __builtin_amdgcn_mfma_f32_16x16x32_bf16(vf, pf, acc[d], 0, 0, 0);
        }
      }
    }

    // epilogue -> LDS aos[token][inner]; wave w fills inner [32w, 32w+32)
    float lg = l;
    lg += __shfl_xor(lg, 16);
    lg += __shfl_xor(lg, 32);
    const float inv = 1.f / lg;
#pragma unroll
    for (int d = 0; d < 2; ++d) {
      ushort4 uo;
      uo.x = f2bf(acc[d][0] * inv);
      uo.y = f2bf(acc[d][1] * inv);
      uo.z = f2bf(acc[d][2] * inv);
      uo.w = f2bf(acc[d][3] * inv);
      *reinterpret_cast<ushort4*>(&u2.aos[qi][w * 32 + d * 16 + 4 * g]) = uo;
    }
  }
  __syncthreads();   // attn done: P dead, aos complete

  const int li = qi;   // lane&15

  // ================= MLP (16-token tile) =================
  // ---- Phase A: out-proj + bias + residual -> t2s (fp32) ----
  {
    bf16x8 Af[4];
#pragma unroll
    for (int ks = 0; ks < 4; ++ks)
      Af[ks] = *reinterpret_cast<const bf16x8*>(&u2.aos[li][ks * 32 + 8 * g]);
#pragma unroll
    for (int nf = 0; nf < 4; ++nf) {
      const int n = w * 64 + nf * 16;
      bf16x8 Bf[4];
#pragma unroll
      for (int ks = 0; ks < 4; ++ks)
        Bf[ks] = *reinterpret_cast<const bf16x8*>(
            &woutT[(size_t)(n + li) * INNER_ + ks * 32 + 8 * g]);
      f32x4 acc = {0.f, 0.f, 0.f, 0.f};
#pragma unroll
      for (int ks = 0; ks < 4; ++ks)
        acc = __builtin_amdgcn_mfma_f32_16x16x32_bf16(Af[ks], Bf[ks], acc, 0, 0, 0);
      const int nch = n + li;
      const int tl0 = 4 * g;
      const float bo = b_out[nch];
#pragma unroll
      for (int r = 0; r < 4; ++r)
        u1.t2s[tl0 + r][nch] =
            acc[r] + bo + bf2f(tokb[((size_t)b * N_ + nq0 + tl0 + r) * C_ + nch]);
    }
  }
  __syncthreads();

  // ---- LN2: 16 threads per token, 16 ch each ----
  {
    const int tl = tid >> 4, c0 = (tid & 15) * 16;
    float v[16];
#pragma unroll
    for (int j = 0; j < 4; ++j) {
      const float4 t4 = *reinterpret_cast<const float4*>(&u1.t2s[tl][c0 + 4 * j]);
      v[4*j] = t4.x; v[4*j+1] = t4.y; v[4*j+2] = t4.z; v[4*j+3] = t4.w;
    }
    float s = 0.f;
#pragma unroll
    for (int i = 0; i < 16; ++i) s += v[i];
    s += __shfl_xor(s, 1); s += __shfl_xor(s, 2);
    s += __shfl_xor(s, 4); s += __shfl_xor(s, 8);
    const float mu = s * (1.f / C_);
    float sq = 0.f;
#pragma unroll
    for (int i = 0; i < 16; ++i) { const float d = v[i] - mu; sq += d * d; }
    sq += __shfl_xor(sq, 1); sq += __shfl_xor(sq, 2);
    sq += __shfl_xor(sq, 4); sq += __shfl_xor(sq, 8);
    const float rs = rsqrtf(sq * (1.f / C_) + EPS_);
#pragma unroll
    for (int j = 0; j < 4; ++j) {
      const float4 gg = *reinterpret_cast<const float4*>(&g2[c0 + 4 * j]);
      const float4 be = *reinterpret_cast<const float4*>(&beta2[c0 + 4 * j]);
      ushort4 uu;
      uu.x = f2bf((v[4*j]   - mu) * rs * gg.x + be.x);
      uu.y = f2bf((v[4*j+1] - mu) * rs * gg.y + be.y);
      uu.z = f2bf((v[4*j+2] - mu) * rs * gg.z + be.z);
      uu.w = f2bf((v[4*j+3] - mu) * rs * gg.w + be.w);
      *reinterpret_cast<ushort4*>(&xn2[tl][c0 + 4 * j]) = uu;
    }
  }
  __syncthreads();

  // ---- Phase B: ff1 + gelu -> hsb (aliases aos; barrier since last read) ----
  {
    bf16x8 Af[8];
#pragma unroll
    for (int ks = 0; ks < 8; ++ks)
      Af[ks] = *reinterpret_cast<const bf16x8*>(&xn2[li][ks * 32 + 8 * g]);
#pragma unroll
    for (int nf = 0; nf < 2; ++nf) {
      const int n = w * 32 + nf * 16;
      bf16x8 Bf[8];
#pragma unroll
      for (int ks = 0; ks < 8; ++ks)
        Bf[ks] = *reinterpret_cast<const bf16x8*>(
            &wff1T[(size_t)(n + li) * C_ + ks * 32 + 8 * g]);
      f32x4 acc = {0.f, 0.f, 0.f, 0.f};
#pragma unroll
      for (int ks = 0; ks < 8; ++ks)
        acc = __builtin_amdgcn_mfma_f32_16x16x32_bf16(Af[ks], Bf[ks], acc, 0, 0, 0);
      const int nch = n + li;
      const int tl0 = 4 * g;
      const float bf1 = b_ff1[nch];
#pragma unroll
      for (int r = 0; r < 4; ++r) {
        float hv = acc[r] + bf1;
        hv = 0.5f * hv * (1.f + erff(hv * 0.70710678118654752f));
        u2.hsb[tl0 + r][nch] = f2bf(hv);
      }
    }
  }
  __syncthreads();

  // ---- Phase C: ff2 + bias + residual -> out (transposed store) ----
  {
    bf16x8 Af[4];
#pragma unroll
    for (int ks = 0; ks < 4; ++ks)
      Af[ks] = *reinterpret_cast<const bf16x8*>(&u2.hsb[li][ks * 32 + 8 * g]);
#pragma unroll
    for (int nf = 0; nf < 4; ++nf) {
      const int n = w * 64 + nf * 16;
      bf16x8 Bf[4];
#pragma unroll
      for (int ks = 0; ks < 4; ++ks)
        Bf[ks] = *reinterpret_cast<const bf16x8*>(
            &wff2T[(size_t)(n + li) * INNER_ + ks * 32 + 8 * g]);
      f32x4 acc = {0.f, 0.f, 0.f, 0.f};
#pragma unroll
      for (int ks = 0; ks < 4; ++ks)
        acc = __builtin_amdgcn_mfma_f32_16x16x32_bf16(Af[ks], Bf[ks], acc, 0, 0, 0);
      const int nch = n + li;
      const int tl0 = 4 * g;
      const float bo = b_ff2[nch];
      float4 o;
      o.x = acc[0] + bo + u1.t2s[tl0 + 0][nch];
      o.y = acc[1] + bo + u1.t2s[tl0 + 1][nch];
      o.z = acc[2] + bo + u1.t2s[tl0 + 2][nch];
      o.w = acc[3] + bo + u1.t2s[tl0 + 3][nch];
      *reinterpret_cast<float4*>(
          &out[((size_t)b * C_ + nch) * N_ + nq0 + tl0]) = o;
    }
  }
}

extern "C" void kernel_launch(void* const* d_in, const int* in_sizes, int n_in,
                              void* d_out, int out_size, void* d_ws, size_t ws_size,
                              hipStream_t stream) {
  const float* x     = (const float*)d_in[0];
  const float* pos   = (const float*)d_in[1];
  const float* w_qkv = (const float*)d_in[2];
  const float* w_out = (const float*)d_in[3];
  const float* b_out = (const float*)d_in[4];
  const float* w_ff1 = (const float*)d_in[5];
  const float* b_ff1 = (const float*)d_in[6];
  const float* w_ff2 = (const float*)d_in[7];
  const float* b_ff2 = (const float*)d_in[8];
  const float* g1    = (const float*)d_in[9];
  const float* beta1 = (const float*)d_in[10];
  const float* g2    = (const float*)d_in[11];
  const float* beta2 = (const float*)d_in[12];
  float* out = (float*)d_out;

  ushort* tokb  = (ushort*)d_ws;                // 4,194,304 bf16
  ushort* qb    = tokb + 4194304;               // 2,097,152
  ushort* kb    = qb + 2097152;
  ushort* vtb   = kb + 2097152;
  ushort* wqkvT = vtb + 2097152;                // 98,304
  ushort* woutT = wqkvT + 98304;                // 32,768
  ushort* wff1T = woutT + 32768;                // 32,768
  ushort* wff2T = wff1T + 32768;                // 32,768

  k_wconv<<<768, 256, 0, stream>>>(w_qkv, w_out, w_ff1, w_ff2,
                                   wqkvT, woutT, wff1T, wff2T);
  k_fused<<<256, 512, 0, stream>>>(x, pos, g1, beta1, wqkvT, tokb, qb, kb, vtb);
  k_attn_mlp<<<1024, 256, 0, stream>>>(qb, kb, vtb, tokb, woutT, b_out,
                                       wff1T, b_ff1, wff2T, b_ff2, g2, beta2, out);
}

// Round 11
// 157.913 us; speedup vs baseline: 1.1508x; 1.1508x over previous
//
#include <hip/hip_runtime.h>
#include <hip/hip_bf16.h>
#include <math.h>

#define B_     16
#define C_     256
#define N_     1024
#define HEADS_ 4
#define DH_    32
#define INNER_ 128
#define EPS_   1e-5f

typedef __attribute__((ext_vector_type(8))) short bf16x8;
typedef __attribute__((ext_vector_type(4))) float f32x4;

__device__ __forceinline__ ushort f2bf(float f) {
  union { float f; unsigned u; } v; v.f = f;
  unsigned u = v.u;
  return (ushort)((u + 0x7fffu + ((u >> 16) & 1u)) >> 16);
}
__device__ __forceinline__ float bf2f(ushort u) {
  union { unsigned u; float f; } v; v.u = ((unsigned)u) << 16;
  return v.f;
}
__device__ __forceinline__ unsigned cvt_pk_bf16(float lo, float hi) {
  unsigned r;
  asm("v_cvt_pk_bf16_f32 %0, %1, %2" : "=v"(r) : "v"(lo), "v"(hi));
  return r;
}

// scale(1/sqrt(32)) * log2(e) folded into Q at QKV time.
// Fixed-base softmax: p = exp2(s) directly (scores bounded ~ +-9).
#define QSCALE_ 0.2550348652979437f

// ---------------- K0: weight convert + transpose to bf16 ----------------
__global__ __launch_bounds__(256) void k_wconv(
    const float* __restrict__ wqkv, const float* __restrict__ wout,
    const float* __restrict__ wff1, const float* __restrict__ wff2,
    ushort* __restrict__ wqkvT, ushort* __restrict__ woutT,
    ushort* __restrict__ wff1T, ushort* __restrict__ wff2T) {
  int i = blockIdx.x * 256 + threadIdx.x;
  if (i < 98304) {                       // w_qkv [256][384] -> [384][256]
    int k = i / 384, n = i % 384;
    wqkvT[n * 256 + k] = f2bf(wqkv[i]);
    return;
  }
  i -= 98304;
  if (i < 32768) {                       // w_out [128][256] -> [256][128]
    int k = i / 256, n = i % 256;
    woutT[n * 128 + k] = f2bf(wout[i]);
    return;
  }
  i -= 32768;
  if (i < 32768) {                       // w_ff1 [256][128] -> [128][256]
    int k = i / 128, n = i % 128;
    wff1T[n * 256 + k] = f2bf(wff1[i]);
    return;
  }
  i -= 32768;
  {                                      // w_ff2 [128][256] -> [256][128]
    int k = i / 256, n = i % 256;
    wff2T[n * 128 + k] = f2bf(wff2[i]);
  }
}

// ---------------- K1: fused pos+LN1+QKV (512 threads) ----------------
union KFusedSmem {
  float  xs[C_][68];      // 69,632 B  (stage A/B)
  ushort xnl[64][264];    // 33,792 B  (stage C)  -- aliased
};

__global__ __launch_bounds__(512) void k_fused(
    const float* __restrict__ x, const float* __restrict__ pos,
    const float* __restrict__ g1, const float* __restrict__ beta1,
    const ushort* __restrict__ wqkvT, ushort* __restrict__ tokb,
    ushort* __restrict__ qb, ushort* __restrict__ kb, ushort* __restrict__ vtb) {
  const int b  = blockIdx.x >> 4;
  const int n0 = (blockIdx.x & 15) << 6;
  const int t  = threadIdx.x;
  __shared__ KFusedSmem u;

  // ---- Stage A: load x tile 256c x 64n (coalesced, 8 float4/thread) ----
  {
    const int nq = t & 15, cq = t >> 4;          // cq 0..31
#pragma unroll
    for (int i = 0; i < 8; ++i) {
      const int c = i * 32 + cq;
      const float4 v = *reinterpret_cast<const float4*>(
          &x[((size_t)b * C_ + c) * N_ + n0 + 4 * nq]);
      *reinterpret_cast<float4*>(&u.xs[c][4 * nq]) = v;
    }
  }
  __syncthreads();

  // ---- Stage B: pos add + LN (8 threads per token, 32 ch each) ----
  {
    const int tl = t >> 3, sub = t & 7, c0 = sub * 32;
    const int n = n0 + tl;
    float v[32];
#pragma unroll
    for (int i = 0; i < 32; ++i) v[i] = u.xs[c0 + i][tl];
#pragma unroll
    for (int j = 0; j < 8; ++j) {
      const float4 p = *reinterpret_cast<const float4*>(&pos[(size_t)n * C_ + c0 + 4 * j]);
      v[4*j] += p.x; v[4*j+1] += p.y; v[4*j+2] += p.z; v[4*j+3] += p.w;
    }
    float s = 0.f;
#pragma unroll
    for (int i = 0; i < 32; ++i) s += v[i];
    s += __shfl_xor(s, 1); s += __shfl_xor(s, 2); s += __shfl_xor(s, 4);
    const float mu = s * (1.f / C_);
    float sq = 0.f;
#pragma unroll
    for (int i = 0; i < 32; ++i) { const float d = v[i] - mu; sq += d * d; }
    sq += __shfl_xor(sq, 1); sq += __shfl_xor(sq, 2); sq += __shfl_xor(sq, 4);
    const float rs = rsqrtf(sq * (1.f / C_) + EPS_);

    ushort* tokrow = &tokb[((size_t)b * N_ + n) * C_ + c0];
    ushort xn_local[32];
#pragma unroll
    for (int j = 0; j < 8; ++j) {
      ushort4 tu;
      tu.x = f2bf(v[4*j]);   tu.y = f2bf(v[4*j+1]);
      tu.z = f2bf(v[4*j+2]); tu.w = f2bf(v[4*j+3]);
      *reinterpret_cast<ushort4*>(&tokrow[4 * j]) = tu;
      const float4 g  = *reinterpret_cast<const float4*>(&g1[c0 + 4 * j]);
      const float4 be = *reinterpret_cast<const float4*>(&beta1[c0 + 4 * j]);
      xn_local[4*j]   = f2bf((v[4*j]   - mu) * rs * g.x + be.x);
      xn_local[4*j+1] = f2bf((v[4*j+1] - mu) * rs * g.y + be.y);
      xn_local[4*j+2] = f2bf((v[4*j+2] - mu) * rs * g.z + be.z);
      xn_local[4*j+3] = f2bf((v[4*j+3] - mu) * rs * g.w + be.w);
    }
    __syncthreads();   // all xs reads complete before aliased writes
#pragma unroll
    for (int j = 0; j < 8; ++j)
      *reinterpret_cast<ushort4*>(&u.xnl[tl][c0 + 4 * j]) =
          *reinterpret_cast<ushort4*>(&xn_local[4 * j]);
  }
  __syncthreads();

  // ---- Stage C: QKV GEMM (M=384 ch, N=64 tok, K=256); wave w -> 48 ch ----
  {
    const int w = t >> 6, lane = t & 63;
    const int li = lane & 15, g = lane >> 4;
#pragma unroll
    for (int mf = 0; mf < 3; ++mf) {
      const int chb = w * 48 + mf * 16;
      bf16x8 Af[8];
#pragma unroll
      for (int ks = 0; ks < 8; ++ks)
        Af[ks] = *reinterpret_cast<const bf16x8*>(
            &wqkvT[(size_t)(chb + li) * C_ + ks * 32 + 8 * g]);
#pragma unroll
      for (int nf = 0; nf < 4; ++nf) {
        bf16x8 Bf[8];
#pragma unroll
        for (int ks = 0; ks < 8; ++ks)
          Bf[ks] = *reinterpret_cast<const bf16x8*>(&u.xnl[nf * 16 + li][ks * 32 + 8 * g]);
        f32x4 acc = {0.f, 0.f, 0.f, 0.f};
#pragma unroll
        for (int ks = 0; ks < 8; ++ks)
          acc = __builtin_amdgcn_mfma_f32_16x16x32_bf16(Af[ks], Bf[ks], acc, 0, 0, 0);
        const int nn = n0 + nf * 16 + li;
        const int ch0 = chb + 4 * g;
        if (ch0 < 128) {                        // q, prescaled
          const int h = ch0 >> 5, dh = ch0 & 31;
          ushort4 uq;
          uq.x = f2bf(acc[0] * QSCALE_); uq.y = f2bf(acc[1] * QSCALE_);
          uq.z = f2bf(acc[2] * QSCALE_); uq.w = f2bf(acc[3] * QSCALE_);
          *reinterpret_cast<ushort4*>(&qb[(((size_t)(b * HEADS_ + h)) * N_ + nn) * DH_ + dh]) = uq;
        } else if (ch0 < 256) {
          const int c2 = ch0 - 128, h = c2 >> 5, dh = c2 & 31;
          ushort4 uk;
          uk.x = f2bf(acc[0]); uk.y = f2bf(acc[1]); uk.z = f2bf(acc[2]); uk.w = f2bf(acc[3]);
          *reinterpret_cast<ushort4*>(&kb[(((size_t)(b * HEADS_ + h)) * N_ + nn) * DH_ + dh]) = uk;
        } else {
          const int c2 = ch0 - 256, h = c2 >> 5, dh = c2 & 31;
          ushort* base = &vtb[(((size_t)(b * HEADS_ + h)) * DH_ + dh) * N_ + nn];
          base[0] = f2bf(acc[0]); base[N_] = f2bf(acc[1]);
          base[2 * N_] = f2bf(acc[2]); base[3 * N_] = f2bf(acc[3]);
        }
      }
    }
  }
}

// ---------------- K2: merged attention + MLP (R9 config + XCD swizzle) ------
// grid 512 = (b, 32-token tile), block 256 = 4 waves; wave w = head w.
// XCD swizzle: round-robin d%8 -> XCD; remap so each XCD's block stream is a
// contiguous original range (~2 batches -> 1MB K/V, L2-resident per XCD).
__global__ __launch_bounds__(256) void k_attn_mlp(
    const ushort* __restrict__ qb, const ushort* __restrict__ kb,
    const ushort* __restrict__ vtb, const ushort* __restrict__ tokb,
    const ushort* __restrict__ woutT, const float* __restrict__ b_out,
    const ushort* __restrict__ wff1T, const float* __restrict__ b_ff1,
    const ushort* __restrict__ wff2T, const float* __restrict__ b_ff2,
    const float* __restrict__ g2, const float* __restrict__ beta2,
    float* __restrict__ out) {
  // T1 bijective XCD swizzle (grid 512, 512 % 8 == 0)
  const int bid = (blockIdx.x & 7) * 64 + (blockIdx.x >> 3);
  const int b   = bid >> 5;
  const int tt  = bid & 31;
  const int nq0 = tt * 32;
  const int tid = threadIdx.x;
  const int w = tid >> 6, lane = tid & 63;
  const int qi = lane & 15, g = lane >> 4;

  __shared__ __align__(16) union {
    ushort P[4][2][16][72];   // attn P round-trip      (18,432 B; stride 72 -> 2-way banks)
    float  t2s[32][260];      // MLP fp32 residual      (33,280 B)
  } u1;
  __shared__ __align__(16) ushort xn2[32][264];   // LN2 out (16,896 B)
  __shared__ __align__(16) union {
    ushort aos[32][136];      // attn output tile        (8,704 B)
    ushort hsb[32][136];      // gelu output (aliased)
  } u2;

  // ================= attention (wave w = head w) =================
  {
    const int bh = b * HEADS_ + w;
    const ushort* Kb = kb  + (size_t)bh * N_ * DH_;
    const ushort* Vt = vtb + (size_t)bh * DH_ * N_;

    bf16x8 qf[2];
#pragma unroll
    for (int G = 0; G < 2; ++G)
      qf[G] = *reinterpret_cast<const bf16x8*>(
          qb + ((size_t)bh * N_ + nq0 + G * 16 + qi) * DH_ + 8 * g);

    f32x4 acc[2][2];
#pragma unroll
    for (int G = 0; G < 2; ++G)
#pragma unroll
      for (int d = 0; d < 2; ++d)
#pragma unroll
        for (int r = 0; r < 4; ++r) acc[G][d][r] = 0.f;
    float l[2] = {0.f, 0.f};

    // preload tile 0
    bf16x8 kf[4], vf[2][2];
#pragma unroll
    for (int kt = 0; kt < 4; ++kt)
      kf[kt] = *reinterpret_cast<const bf16x8*>(
          Kb + (size_t)(kt * 16 + qi) * DH_ + 8 * g);
#pragma unroll
    for (int c = 0; c < 2; ++c)
#pragma unroll
      for (int d = 0; d < 2; ++d)
        vf[c][d] = *reinterpret_cast<const bf16x8*>(
            Vt + (size_t)(d * 16 + qi) * N_ + c * 32 + 8 * g);

    for (int jt = 0; jt < 16; ++jt) {
      const int kn = (jt < 15 ? jt + 1 : 15) * 64;
      bf16x8 kfn[4], vfn[2][2];
#pragma unroll
      for (int kt = 0; kt < 4; ++kt)
        kfn[kt] = *reinterpret_cast<const bf16x8*>(
            Kb + (size_t)(kn + kt * 16 + qi) * DH_ + 8 * g);
#pragma unroll
      for (int c = 0; c < 2; ++c)
#pragma unroll
        for (int d = 0; d < 2; ++d)
          vfn[c][d] = *reinterpret_cast<const bf16x8*>(
              Vt + (size_t)(d * 16 + qi) * N_ + kn + c * 32 + 8 * g);

      // ---- S^T = K.Q^T ----
      f32x4 s[2][4];
#pragma unroll
      for (int G = 0; G < 2; ++G)
#pragma unroll
        for (int kt = 0; kt < 4; ++kt) {
          f32x4 z = {0.f, 0.f, 0.f, 0.f};
          s[G][kt] = __builtin_amdgcn_mfma_f32_16x16x32_bf16(kf[kt], qf[G], z, 0, 0, 0);
        }

      // ---- fixed-base softmax: p = exp2(s), all independent ----
#pragma unroll
      for (int G = 0; G < 2; ++G) {
        float psum = 0.f;
#pragma unroll
        for (int kt = 0; kt < 4; ++kt) {
          const float p0 = exp2f(s[G][kt][0]);
          const float p1 = exp2f(s[G][kt][1]);
          const float p2 = exp2f(s[G][kt][2]);
          const float p3 = exp2f(s[G][kt][3]);
          psum += (p0 + p1) + (p2 + p3);
          uint2 dw;
          dw.x = cvt_pk_bf16(p0, p1);
          dw.y = cvt_pk_bf16(p2, p3);
          *reinterpret_cast<uint2*>(&u1.P[w][G][qi][kt * 16 + 4 * g]) = dw;
        }
        l[G] += psum;
      }

      // ---- O^T += Vt . P^T ----
#pragma unroll
      for (int c = 0; c < 2; ++c) {
        const bf16x8 pf0 = *reinterpret_cast<const bf16x8*>(&u1.P[w][0][qi][c * 32 + 8 * g]);
        const bf16x8 pf1 = *reinterpret_cast<const bf16x8*>(&u1.P[w][1][qi][c * 32 + 8 * g]);
#pragma unroll
        for (int d = 0; d < 2; ++d) {
          acc[0][d] = __builtin_amdgcn_mfma_f32_16x16x32_bf16(vf[c][d], pf0, acc[0][d], 0, 0, 0);
          acc[1][d] = __builtin_amdgcn_mfma_f32_16x16x32_bf16(vf[c][d], pf1, acc[1][d], 0, 0, 0);
        }
      }

#pragma unroll
      for (int kt = 0; kt < 4; ++kt) kf[kt] = kfn[kt];
#pragma unroll
      for (int c = 0; c < 2; ++c)
#pragma unroll
        for (int d = 0; d < 2; ++d) vf[c][d] = vfn[c][d];
    }

    // epilogue -> LDS aos[token][inner]; wave w fills inner [32w, 32w+32)
#pragma unroll
    for (int G = 0; G < 2; ++G) {
      float lg = l[G];
      lg += __shfl_xor(lg, 16);
      lg += __shfl_xor(lg, 32);
      const float inv = 1.f / lg;
      const int nloc = G * 16 + qi;
#pragma unroll
      for (int d = 0; d < 2; ++d) {
        ushort4 uo;
        uo.x = f2bf(acc[G][d][0] * inv);
        uo.y = f2bf(acc[G][d][1] * inv);
        uo.z = f2bf(acc[G][d][2] * inv);
        uo.w = f2bf(acc[G][d][3] * inv);
        *reinterpret_cast<ushort4*>(&u2.aos[nloc][w * 32 + d * 16 + 4 * g]) = uo;
      }
    }
  }
  __syncthreads();   // attn done: P dead, aos complete

  const int li = qi;   // lane&15

  // ================= MLP =================
  // ---- Phase A: out-proj + bias + residual -> t2s (fp32) ----
  {
    bf16x8 Af[2][4];
#pragma unroll
    for (int mf = 0; mf < 2; ++mf)
#pragma unroll
      for (int ks = 0; ks < 4; ++ks)
        Af[mf][ks] = *reinterpret_cast<const bf16x8*>(&u2.aos[mf * 16 + li][ks * 32 + 8 * g]);
#pragma unroll
    for (int nf = 0; nf < 4; ++nf) {
      const int n = w * 64 + nf * 16;
      bf16x8 Bf[4];
#pragma unroll
      for (int ks = 0; ks < 4; ++ks)
        Bf[ks] = *reinterpret_cast<const bf16x8*>(
            &woutT[(size_t)(n + li) * INNER_ + ks * 32 + 8 * g]);
#pragma unroll
      for (int mf = 0; mf < 2; ++mf) {
        f32x4 acc = {0.f, 0.f, 0.f, 0.f};
#pragma unroll
        for (int ks = 0; ks < 4; ++ks)
          acc = __builtin_amdgcn_mfma_f32_16x16x32_bf16(Af[mf][ks], Bf[ks], acc, 0, 0, 0);
        const int nch = n + li;
        const int tl0 = mf * 16 + 4 * g;
        const float bo = b_out[nch];
#pragma unroll
        for (int r = 0; r < 4; ++r)
          u1.t2s[tl0 + r][nch] =
              acc[r] + bo + bf2f(tokb[((size_t)b * N_ + nq0 + tl0 + r) * C_ + nch]);
      }
    }
  }
  __syncthreads();

  // ---- LN2: 8 threads per token ----
  {
    const int tl = tid >> 3, c0 = (tid & 7) * 32;
    float v[32];
#pragma unroll
    for (int j = 0; j < 8; ++j) {
      const float4 t4 = *reinterpret_cast<const float4*>(&u1.t2s[tl][c0 + 4 * j]);
      v[4*j] = t4.x; v[4*j+1] = t4.y; v[4*j+2] = t4.z; v[4*j+3] = t4.w;
    }
    float s = 0.f;
#pragma unroll
    for (int i = 0; i < 32; ++i) s += v[i];
    s += __shfl_xor(s, 1); s += __shfl_xor(s, 2); s += __shfl_xor(s, 4);
    const float mu = s * (1.f / C_);
    float sq = 0.f;
#pragma unroll
    for (int i = 0; i < 32; ++i) { const float d = v[i] - mu; sq += d * d; }
    sq += __shfl_xor(sq, 1); sq += __shfl_xor(sq, 2); sq += __shfl_xor(sq, 4);
    const float rs = rsqrtf(sq * (1.f / C_) + EPS_);
#pragma unroll
    for (int j = 0; j < 8; ++j) {
      const float4 gg = *reinterpret_cast<const float4*>(&g2[c0 + 4 * j]);
      const float4 be = *reinterpret_cast<const float4*>(&beta2[c0 + 4 * j]);
      ushort4 uu;
      uu.x = f2bf((v[4*j]   - mu) * rs * gg.x + be.x);
      uu.y = f2bf((v[4*j+1] - mu) * rs * gg.y + be.y);
      uu.z = f2bf((v[4*j+2] - mu) * rs * gg.z + be.z);
      uu.w = f2bf((v[4*j+3] - mu) * rs * gg.w + be.w);
      *reinterpret_cast<ushort4*>(&xn2[tl][c0 + 4 * j]) = uu;
    }
  }
  __syncthreads();

  // ---- Phase B: ff1 + gelu -> hsb (aliases aos; 2 barriers since last read) ----
  {
    bf16x8 Af[2][8];
#pragma unroll
    for (int mf = 0; mf < 2; ++mf)
#pragma unroll
      for (int ks = 0; ks < 8; ++ks)
        Af[mf][ks] = *reinterpret_cast<const bf16x8*>(&xn2[mf * 16 + li][ks * 32 + 8 * g]);
#pragma unroll
    for (int nf = 0; nf < 2; ++nf) {
      const int n = w * 32 + nf * 16;
      bf16x8 Bf[8];
#pragma unroll
      for (int ks = 0; ks < 8; ++ks)
        Bf[ks] = *reinterpret_cast<const bf16x8*>(
            &wff1T[(size_t)(n + li) * C_ + ks * 32 + 8 * g]);
#pragma unroll
      for (int mf = 0; mf < 2; ++mf) {
        f32x4 acc = {0.f, 0.f, 0.f, 0.f};
#pragma unroll
        for (int ks = 0; ks < 8; ++ks)
          acc = __builtin_amdgcn_mfma_f32_16x16x32_bf16(Af[mf][ks], Bf[ks], acc, 0, 0, 0);
        const int nch = n + li;
        const int tl0 = mf * 16 + 4 * g;
        const float bf1 = b_ff1[nch];
#pragma unroll
        for (int r = 0; r < 4; ++r) {
          float hv = acc[r] + bf1;
          hv = 0.5f * hv * (1.f + erff(hv * 0.70710678118654752f));
          u2.hsb[tl0 + r][nch] = f2bf(hv);
        }
      }
    }
  }
  __syncthreads();

  // ---- Phase C: ff2 + bias + residual -> out (transposed store) ----
  {
    bf16x8 Af[2][4];
#pragma unroll
    for (int mf = 0; mf < 2; ++mf)
#pragma unroll
      for (int ks = 0; ks < 4; ++ks)
        Af[mf][ks] = *reinterpret_cast<const bf16x8*>(&u2.hsb[mf * 16 + li][ks * 32 + 8 * g]);
#pragma unroll
    for (int nf = 0; nf < 4; ++nf) {
      const int n = w * 64 + nf * 16;
      bf16x8 Bf[4];
#pragma unroll
      for (int ks = 0; ks < 4; ++ks)
        Bf[ks] = *reinterpret_cast<const bf16x8*>(
            &wff2T[(size_t)(n + li) * INNER_ + ks * 32 + 8 * g]);
#pragma unroll
      for (int mf = 0; mf < 2; ++mf) {
        f32x4 acc = {0.f, 0.f, 0.f, 0.f};
#pragma unroll
        for (int ks = 0; ks < 4; ++ks)
          acc = __builtin_amdgcn_mfma_f32_16x16x32_bf16(Af[mf][ks], Bf[ks], acc, 0, 0, 0);
        const int nch = n + li;
        const int tl0 = mf * 16 + 4 * g;
        const float bo = b_ff2[nch];
        float4 o;
        o.x = acc[0] + bo + u1.t2s[tl0 + 0][nch];
        o.y = acc[1] + bo + u1.t2s[tl0 + 1][nch];
        o.z = acc[2] + bo + u1.t2s[tl0 + 2][nch];
        o.w = acc[3] + bo + u1.t2s[tl0 + 3][nch];
        *reinterpret_cast<float4*>(
            &out[((size_t)b * C_ + nch) * N_ + nq0 + tl0]) = o;
      }
    }
  }
}

extern "C" void kernel_launch(void* const* d_in, const int* in_sizes, int n_in,
                              void* d_out, int out_size, void* d_ws, size_t ws_size,
                              hipStream_t stream) {
  const float* x     = (const float*)d_in[0];
  const float* pos   = (const float*)d_in[1];
  const float* w_qkv = (const float*)d_in[2];
  const float* w_out = (const float*)d_in[3];
  const float* b_out = (const float*)d_in[4];
  const float* w_ff1 = (const float*)d_in[5];
  const float* b_ff1 = (const float*)d_in[6];
  const float* w_ff2 = (const float*)d_in[7];
  const float* b_ff2 = (const float*)d_in[8];
  const float* g1    = (const float*)d_in[9];
  const float* beta1 = (const float*)d_in[10];
  const float* g2    = (const float*)d_in[11];
  const float* beta2 = (const float*)d_in[12];
  float* out = (float*)d_out;

  ushort* tokb  = (ushort*)d_ws;                // 4,194,304 bf16
  ushort* qb    = tokb + 4194304;               // 2,097,152
  ushort* kb    = qb + 2097152;
  ushort* vtb   = kb + 2097152;
  ushort* wqkvT = vtb + 2097152;                // 98,304
  ushort* woutT = wqkvT + 98304;                // 32,768
  ushort* wff1T = woutT + 32768;                // 32,768
  ushort* wff2T = wff1T + 32768;                // 32,768

  k_wconv<<<768, 256, 0, stream>>>(w_qkv, w_out, w_ff1, w_ff2,
                                   wqkvT, woutT, wff1T, wff2T);
  k_fused<<<256, 512, 0, stream>>>(x, pos, g1, beta1, wqkvT, tokb, qb, kb, vtb);
  k_attn_mlp<<<512, 256, 0, stream>>>(qb, kb, vtb, tokb, woutT, b_out,
                                      wff1T, b_ff1, wff2T, b_ff2, g2, beta2, out);
}